// Round 15
// baseline (1566.409 us; speedup 1.0000x reference)
//
#include <hip/hip_runtime.h>
#include <cmath>

// R15: wavefront LSTM, LDS-pipe + chain cuts. vs R14:
//  - 8 waves x 3-4 tiles (was 14 x 2): A-operand broadcast ds_read_b128
//    112 -> 64 per step (LDS has no cross-wave multicast; cost scales with
//    wave count). 512-thread barriers. Tiles: w<4 -> 4 tiles, else 3 (28 >= 27).
//  - accx pipelining (R11-validated): x-part MFMAs for ss+1 run in the
//    post-B1 window of ss -> 4 MFMA latencies off the serial h-chain.
//  - GST 436->434: gate-write kg bank-windows 0/8/16/24 (4-distinct).
// Macro-batched consume (K=8), tagged relaxed handoff, fragment maps: R14.

namespace {
constexpr int H = 106, G4 = 424, SEQ = 512, BB = 256, KIN0 = 100;
constexpr int GST = 434;            // gates row stride (f32)
constexpr int NTHR = 512;           // 8 waves
constexpr int RGN = 16;             // rowgroups (16 rows each)
constexpr int NLAYER = 11;
constexpr int RD = 16;              // ring depth (steps)
constexpr int REL = 56;             // u64 elements per ring row
constexpr int KMAC = 8;             // macro size (steps)
constexpr size_t CNT_STRIDE = 16;
constexpr size_t RING_OFF_B = 65536;
constexpr size_t RING_PER_L = (size_t)RD * BB * REL;   // u64 elements

using f16x8 = __attribute__((ext_vector_type(8))) _Float16;
using f32x4 = __attribute__((ext_vector_type(4))) float;
typedef unsigned long long u64;

__device__ __forceinline__ u64 ald(const u64* p) {
    return __hip_atomic_load(p, __ATOMIC_RELAXED, __HIP_MEMORY_SCOPE_AGENT);
}
__device__ __forceinline__ void ast(u64* p, u64 v) {
    __hip_atomic_store(p, v, __ATOMIC_RELAXED, __HIP_MEMORY_SCOPE_AGENT);
}
__device__ __forceinline__ unsigned aldu(const unsigned* p) {
    return __hip_atomic_load(p, __ATOMIC_RELAXED, __HIP_MEMORY_SCOPE_AGENT);
}
__device__ __forceinline__ void astu(unsigned* p, unsigned v) {
    __hip_atomic_store(p, v, __ATOMIC_RELAXED, __HIP_MEMORY_SCOPE_AGENT);
}
__device__ __forceinline__ void spinc(const unsigned* p, unsigned tgt) {
    while (aldu(p) < tgt) __builtin_amdgcn_s_sleep(8);
}
__device__ __forceinline__ float fast_tanh(float x) {
    float t = __expf(2.0f * x);
    return 1.0f - 2.0f / (t + 1.0f);
}
__device__ __forceinline__ float act_gate(float g, bool istanh) {
    float s = istanh ? 2.0f * g : g;
    float r = 1.0f / (1.0f + __expf(-s));
    return istanh ? 2.0f * r - 1.0f : r;
}
__device__ __forceinline__ unsigned packh2(float a, float b) {
    unsigned lo = (unsigned)__builtin_bit_cast(unsigned short, (_Float16)a);
    unsigned hi = (unsigned)__builtin_bit_cast(unsigned short, (_Float16)b);
    return (hi << 16) | lo;
}

__global__ __launch_bounds__(NTHR)
__attribute__((amdgpu_waves_per_eu(2, 2)))
void lstm_wave(const float* __restrict__ noise,   // (512,256,100) f32
               float* __restrict__ yout,          // (512,256,106) f32
               unsigned* cnt, u64* ring,
               const float* __restrict__ W_ih0, const float* __restrict__ W_hh0,
               const float* __restrict__ b_ih0, const float* __restrict__ b_hh0,
               const float* __restrict__ W_ih,  const float* __restrict__ W_hh,
               const float* __restrict__ b_ih,  const float* __restrict__ b_hh)
{
    const int l = blockIdx.x / RGN;
    const int rg = blockIdx.x % RGN;
    const bool LAST = (l == NLAYER - 1);
    const int K_IN = (l == 0) ? KIN0 : H;

    const float* Wih = (l == 0) ? W_ih0 : W_ih + (size_t)(l - 1) * G4 * H;
    const float* Whh = (l == 0) ? W_hh0 : W_hh + (size_t)(l - 1) * G4 * H;
    const float* pbi = (l == 0) ? b_ih0 : b_ih + (size_t)(l - 1) * G4;
    const float* pbh = (l == 0) ? b_hh0 : b_hh + (size_t)(l - 1) * G4;

    unsigned* cons_my = cnt + (size_t)(l * RGN + rg) * CNT_STRIDE;
    unsigned* cons_in = cnt + (size_t)((l - 1) * RGN + rg) * CNT_STRIDE;
    u64* ring_in  = ring + (size_t)(l - 1) * RING_PER_L;
    u64* ring_out = ring + (size_t)l * RING_PER_L;

    __shared__ __align__(16) _Float16 sx[KMAC][16 * 136];  // 34.8 KB
    __shared__ __align__(16) _Float16 sh[16 * 136];        //  4.4 KB
    __shared__ __align__(16) float gl[16 * GST];           // 27.8 KB

    const int tid = threadIdx.x;
    const int w = tid >> 6, lane = tid & 63;
    const int l16 = lane & 15, kg = lane >> 4;
    const int NT = (w < 4) ? 4 : 3;                // tiles this wave
    const int tb = (w < 4) ? 4 * w : 16 + 3 * (w - 4);

    // ---- weights: NT N-tiles/wave, 8 k-steps (same fragment map) ----
    f16x8 bf[4][8];
    float bias[4];
    #pragma unroll
    for (int t = 0; t < 4; ++t) {
        const int n = 16 * (tb + t) + l16;
        const bool valid = (t < NT) && (n < G4);
        const float* pwx = Wih + (size_t)(valid ? n : 0) * K_IN;
        const float* pwh = Whh + (size_t)(valid ? n : 0) * H;
        #pragma unroll
        for (int q = 0; q < 8; ++q) {
            f16x8 v;
            #pragma unroll
            for (int e = 0; e < 8; ++e) {
                const int k = 32 * q + 8 * kg + e;
                float f = 0.0f;
                if (valid) {
                    if (k < 128) { if (k < K_IN) f = pwx[k]; }
                    else { const int kh = k - 128; if (kh < H) f = pwh[kh]; }
                }
                v[e] = (_Float16)f;
            }
            bf[t][q] = v;
        }
        bias[t] = valid ? (pbi[n] + pbh[n]) : 0.0f;
    }

    // ---- init: zero sx (all slots) + sh ----
    for (int i = tid; i < KMAC * 1088 + 1088; i += NTHR) {
        if (i < KMAC * 1088) ((unsigned*)sx)[i] = 0;
        else ((unsigned*)sh)[i - KMAC * 1088] = 0;
    }
    float c0[2] = {0.f, 0.f}, c1[2] = {0.f, 0.f};
    __syncthreads();

    f32x4 accx[4];

    for (int m = 0; m < SEQ / KMAC; ++m) {
        // ---- acquire x bundle for steps 8m..8m+7 (2 flat items/thread) ----
        #pragma unroll
        for (int e = 0; e < 2; ++e) {
            const int flat = tid + NTHR * e;
            if (flat < 896) {
                const int lm = flat / 56, ld = flat % 56;
                unsigned xw[KMAC];
                if (l == 0) {
                    #pragma unroll
                    for (int ss = 0; ss < KMAC; ++ss) {
                        unsigned r = 0;
                        if (ld < 50) {
                            const int s = KMAC * m + ss;
                            const float2 t = *(const float2*)(noise +
                                ((size_t)s * BB + rg * 16 + lm) * KIN0 + 2 * ld);
                            r = packh2(t.x, t.y);
                        }
                        xw[ss] = r;
                    }
                } else {
                    u64 v[KMAC];
                    #pragma unroll
                    for (int ss = 0; ss < KMAC; ++ss) {   // issue all (MLP)
                        const int s = KMAC * m + ss;
                        v[ss] = ald(ring_in + ((size_t)(s & (RD - 1)) * BB + rg * 16 + lm) * REL + ld);
                    }
                    #pragma unroll
                    for (int ss = 0; ss < KMAC; ++ss) {   // verify tags
                        const int s = KMAC * m + ss;
                        const unsigned expt = (unsigned)(s + 1);
                        const u64* pin = ring_in + ((size_t)(s & (RD - 1)) * BB + rg * 16 + lm) * REL + ld;
                        u64 vv = v[ss];
                        while ((unsigned)(vv >> 32) != expt) { __builtin_amdgcn_s_sleep(2); vv = ald(pin); }
                        xw[ss] = (unsigned)vv;
                    }
                }
                if (l > 0 || ld < 50) {
                    #pragma unroll
                    for (int ss = 0; ss < KMAC; ++ss)
                        ((unsigned*)sx)[ss * 1088 + lm * 68 + ld] = xw[ss];
                }
            }
        }
        // producer backpressure, once per macro (validated R14)
        if (tid == 0 && !LAST && m >= 2) spinc(cons_my, (unsigned)(KMAC * m - 8));
        __syncthreads();   // install done; acquire loads drained
        if (tid == 0 && l > 0) astu(cons_in, (unsigned)(KMAC * m + KMAC));

        // ---- accx for substep 0 ----
        {
            #pragma unroll
            for (int t = 0; t < 4; ++t) accx[t] = f32x4{0, 0, 0, 0};
            const _Float16* ax = &sx[0][l16 * 136 + 8 * kg];
            #pragma unroll
            for (int q = 0; q < 4; ++q) {
                const f16x8 a = *(const f16x8*)(ax + 32 * q);
                #pragma unroll
                for (int t = 0; t < 4; ++t)
                    if (t < NT)
                        accx[t] = __builtin_amdgcn_mfma_f32_16x16x32_f16(a, bf[t][q], accx[t], 0, 0, 0);
            }
        }

        // ---- 8 substeps ----
        for (int ss = 0; ss < KMAC; ++ss) {
            const int s = KMAC * m + ss;
            // h-part MFMAs, C init = accx
            f32x4 acc[4];
            #pragma unroll
            for (int t = 0; t < 4; ++t) acc[t] = accx[t];
            const _Float16* ah = &sh[l16 * 136 + 8 * kg];
            #pragma unroll
            for (int q = 4; q < 8; ++q) {
                const f16x8 a = *(const f16x8*)(ah + 32 * (q - 4));
                #pragma unroll
                for (int t = 0; t < 4; ++t)
                    if (t < NT)
                        acc[t] = __builtin_amdgcn_mfma_f32_16x16x32_f16(a, bf[t][q], acc[t], 0, 0, 0);
            }
            // activation -> gl. C map: row=4*kg+r, col=l16 (validated).
            #pragma unroll
            for (int t = 0; t < 4; ++t) {
                const int n = 16 * (tb + t) + l16;
                if (t < NT && n < G4) {
                    const bool istanh = (n >= 2 * H) && (n < 3 * H);
                    #pragma unroll
                    for (int r = 0; r < 4; ++r)
                        gl[(4 * kg + r) * GST + n] = act_gate(acc[t][r] + bias[t], istanh);
                }
            }
            __syncthreads();   // B1: gates ready; sh reads of this substep done

            // state update + publish (2 items/thread) ...
            #pragma unroll
            for (int e = 0; e < 2; ++e) {
                const int item = tid + NTHR * e;
                if (item < 848) {
                    const int um = item / 53, up = item % 53;
                    const float* gm = gl + um * GST;
                    const float2 vi = *(const float2*)(gm + 2 * up);
                    const float2 vf = *(const float2*)(gm + H + 2 * up);
                    const float2 vg = *(const float2*)(gm + 2 * H + 2 * up);
                    const float2 vo = *(const float2*)(gm + 3 * H + 2 * up);
                    c0[e] = fmaf(vf.x, c0[e], vi.x * vg.x);
                    c1[e] = fmaf(vf.y, c1[e], vi.y * vg.y);
                    const float h0 = vo.x * fast_tanh(c0[e]);
                    const float h1 = vo.y * fast_tanh(c1[e]);
                    const unsigned hw = packh2(h0, h1);
                    ((unsigned*)sh)[um * 68 + up] = hw;
                    if (LAST) {
                        *(float2*)(yout + ((size_t)s * BB + rg * 16 + um) * H + 2 * up) =
                            make_float2(h0, h1);
                    } else {
                        ast(ring_out + ((size_t)(s & (RD - 1)) * BB + rg * 16 + um) * REL + up,
                            ((u64)(unsigned)(s + 1) << 32) | hw);
                    }
                } else if (item < 896 && !LAST) {   // pad elements, tagged
                    const int t2 = item - 848, mm = t2 / 3, dd = t2 % 3;
                    ast(ring_out + ((size_t)(s & (RD - 1)) * BB + rg * 16 + mm) * REL + 53 + dd,
                        (u64)(unsigned)(s + 1) << 32);
                }
            }
            // ... overlapped with accx for substep ss+1 (reads sx only)
            if (ss + 1 < KMAC) {
                #pragma unroll
                for (int t = 0; t < 4; ++t) accx[t] = f32x4{0, 0, 0, 0};
                const _Float16* ax = &sx[ss + 1][l16 * 136 + 8 * kg];
                #pragma unroll
                for (int q = 0; q < 4; ++q) {
                    const f16x8 a = *(const f16x8*)(ax + 32 * q);
                    #pragma unroll
                    for (int t = 0; t < 4; ++t)
                        if (t < NT)
                            accx[t] = __builtin_amdgcn_mfma_f32_16x16x32_f16(a, bf[t][q], accx[t], 0, 0, 0);
                }
            }
            __syncthreads();   // B2: h_s visible for next substep
        }
    }
}
}  // namespace

extern "C" void kernel_launch(void* const* d_in, const int* in_sizes, int n_in,
                              void* d_out, int out_size, void* d_ws, size_t ws_size,
                              hipStream_t stream) {
    const float* noise = (const float*)d_in[0];
    const float* W_ih0 = (const float*)d_in[1];
    const float* W_hh0 = (const float*)d_in[2];
    const float* b_ih0 = (const float*)d_in[3];
    const float* b_hh0 = (const float*)d_in[4];
    const float* W_ih  = (const float*)d_in[5];
    const float* W_hh  = (const float*)d_in[6];
    const float* b_ih  = (const float*)d_in[7];
    const float* b_hh  = (const float*)d_in[8];

    // clear counters + rings each call (replay-safe)
    const size_t clear_bytes = RING_OFF_B + (size_t)10 * RING_PER_L * sizeof(u64);
    hipMemsetAsync(d_ws, 0, clear_bytes, stream);

    unsigned* cnt = (unsigned*)d_ws;
    u64* ring = (u64*)((char*)d_ws + RING_OFF_B);

    lstm_wave<<<dim3(NLAYER * RGN), dim3(NTHR), 0, stream>>>(
        noise, (float*)d_out, cnt, ring,
        W_ih0, W_hh0, b_ih0, b_hh0, W_ih, W_hh, b_ih, b_hh);
}

// Round 16
// 1301.594 us; speedup vs baseline: 1.2035x; 1.2035x over previous
//
#include <hip/hip_runtime.h>
#include <cmath>

// R16 = R14 (best: 1287us) + LDS-ONLY BARRIERS.
// __syncthreads() emits s_waitcnt vmcnt(0) lgkmcnt(0) before s_barrier -> every
// substep's B2 drained the fire-and-forget ring stores to the IC coherence
// point (~500-900cyc ack) although no thread in the block needs them. Replace
// with s_waitcnt lgkmcnt(0) (asm, sched_barrier-fenced per guide rule #18) +
// raw s_barrier: LDS ordering preserved, global stores retire lazily (tag is
// in the same u64 atom -> consumer ordering unaffected; <=16 in flight).
// Everything else byte-identical to R14.

namespace {
constexpr int H = 106, G4 = 424, SEQ = 512, BB = 256, KIN0 = 100;
constexpr int GST = 436;            // gates row stride (f32)
constexpr int NTHR = 896;           // 14 waves
constexpr int RGN = 16;             // rowgroups (16 rows each)
constexpr int NLAYER = 11;
constexpr int RD = 16;              // ring depth (steps); 2 macros
constexpr int REL = 56;             // u64 elements per ring row
constexpr int KMAC = 8;             // macro size (steps)
constexpr size_t CNT_STRIDE = 16;   // dwords per counter (64B)
constexpr size_t RING_OFF_B = 65536;
constexpr size_t RING_PER_L = (size_t)RD * BB * REL;   // u64 elements

using f16x8 = __attribute__((ext_vector_type(8))) _Float16;
using f32x4 = __attribute__((ext_vector_type(4))) float;
typedef unsigned long long u64;

__device__ __forceinline__ u64 ald(const u64* p) {
    return __hip_atomic_load(p, __ATOMIC_RELAXED, __HIP_MEMORY_SCOPE_AGENT);
}
__device__ __forceinline__ void ast(u64* p, u64 v) {
    __hip_atomic_store(p, v, __ATOMIC_RELAXED, __HIP_MEMORY_SCOPE_AGENT);
}
__device__ __forceinline__ unsigned aldu(const unsigned* p) {
    return __hip_atomic_load(p, __ATOMIC_RELAXED, __HIP_MEMORY_SCOPE_AGENT);
}
__device__ __forceinline__ void astu(unsigned* p, unsigned v) {
    __hip_atomic_store(p, v, __ATOMIC_RELAXED, __HIP_MEMORY_SCOPE_AGENT);
}
__device__ __forceinline__ void spinc(const unsigned* p, unsigned tgt) {
    while (aldu(p) < tgt) __builtin_amdgcn_s_sleep(8);
}
// Barrier that does NOT drain vmcnt (global stores stay in flight).
__device__ __forceinline__ void barrier_lds() {
    asm volatile("s_waitcnt lgkmcnt(0)" ::: "memory");
    __builtin_amdgcn_sched_barrier(0);
    __builtin_amdgcn_s_barrier();
    __builtin_amdgcn_sched_barrier(0);
}
__device__ __forceinline__ float fast_tanh(float x) {
    float t = __expf(2.0f * x);
    return 1.0f - 2.0f / (t + 1.0f);
}
__device__ __forceinline__ float act_gate(float g, bool istanh) {
    float s = istanh ? 2.0f * g : g;
    float r = 1.0f / (1.0f + __expf(-s));
    return istanh ? 2.0f * r - 1.0f : r;
}
__device__ __forceinline__ unsigned packh2(float a, float b) {
    unsigned lo = (unsigned)__builtin_bit_cast(unsigned short, (_Float16)a);
    unsigned hi = (unsigned)__builtin_bit_cast(unsigned short, (_Float16)b);
    return (hi << 16) | lo;
}

__global__ __launch_bounds__(NTHR)
__attribute__((amdgpu_waves_per_eu(4, 4)))
void lstm_wave(const float* __restrict__ noise,   // (512,256,100) f32
               float* __restrict__ yout,          // (512,256,106) f32
               unsigned* cnt, u64* ring,
               const float* __restrict__ W_ih0, const float* __restrict__ W_hh0,
               const float* __restrict__ b_ih0, const float* __restrict__ b_hh0,
               const float* __restrict__ W_ih,  const float* __restrict__ W_hh,
               const float* __restrict__ b_ih,  const float* __restrict__ b_hh)
{
    const int l = blockIdx.x / RGN;
    const int rg = blockIdx.x % RGN;
    const bool LAST = (l == NLAYER - 1);
    const int K_IN = (l == 0) ? KIN0 : H;

    const float* Wih = (l == 0) ? W_ih0 : W_ih + (size_t)(l - 1) * G4 * H;
    const float* Whh = (l == 0) ? W_hh0 : W_hh + (size_t)(l - 1) * G4 * H;
    const float* pbi = (l == 0) ? b_ih0 : b_ih + (size_t)(l - 1) * G4;
    const float* pbh = (l == 0) ? b_hh0 : b_hh + (size_t)(l - 1) * G4;

    unsigned* cons_my = cnt + (size_t)(l * RGN + rg) * CNT_STRIDE;
    unsigned* cons_in = cnt + (size_t)((l - 1) * RGN + rg) * CNT_STRIDE;
    u64* ring_in  = ring + (size_t)(l - 1) * RING_PER_L;
    u64* ring_out = ring + (size_t)l * RING_PER_L;

    __shared__ __align__(16) _Float16 sx[KMAC][16 * 136];  // 34.8 KB
    __shared__ __align__(16) _Float16 sh[16 * 136];        //  4.4 KB
    __shared__ float gl[16 * GST];                         // 27.9 KB

    const int tid = threadIdx.x;
    const int w = tid >> 6, lane = tid & 63;
    const int l16 = lane & 15, kg = lane >> 4;
    const int lm = tid / 56, ld = tid % 56;   // loader map (row, element)
    const int um = tid / 53, up = tid % 53;   // update map (row, H-pair)

    // ---- weights: 2 N-tiles/wave, 8 k-steps (validated R8-R15) ----
    f16x8 bf[2][8];
    float bias[2];
    #pragma unroll
    for (int t = 0; t < 2; ++t) {
        const int n = 16 * (2 * w + t) + l16;
        const bool valid = n < G4;
        const float* pwx = Wih + (size_t)(valid ? n : 0) * K_IN;
        const float* pwh = Whh + (size_t)(valid ? n : 0) * H;
        #pragma unroll
        for (int q = 0; q < 8; ++q) {
            f16x8 v;
            #pragma unroll
            for (int e = 0; e < 8; ++e) {
                const int k = 32 * q + 8 * kg + e;
                float f = 0.0f;
                if (valid) {
                    if (k < 128) { if (k < K_IN) f = pwx[k]; }
                    else { const int kh = k - 128; if (kh < H) f = pwh[kh]; }
                }
                v[e] = (_Float16)f;
            }
            bf[t][q] = v;
        }
        bias[t] = valid ? (pbi[n] + pbh[n]) : 0.0f;
    }

    // ---- init: zero sx (all slots) + sh ----
    for (int i = tid; i < KMAC * 1088 + 1088; i += NTHR) {
        if (i < KMAC * 1088) ((unsigned*)sx)[i] = 0;
        else ((unsigned*)sh)[i - KMAC * 1088] = 0;
    }
    float c0 = 0.0f, c1 = 0.0f;
    __syncthreads();

    for (int m = 0; m < SEQ / KMAC; ++m) {
        // ---- acquire: x bundle for steps 8m..8m+7 ----
        unsigned xw[KMAC] = {0, 0, 0, 0, 0, 0, 0, 0};
        if (l == 0) {
            if (ld < 50) {
                #pragma unroll
                for (int ss = 0; ss < KMAC; ++ss) {
                    const int s = KMAC * m + ss;
                    const float2 t = *(const float2*)(noise +
                        ((size_t)s * BB + rg * 16 + lm) * KIN0 + 2 * ld);
                    xw[ss] = packh2(t.x, t.y);
                }
            }
        } else {
            u64 v[KMAC];
            #pragma unroll
            for (int ss = 0; ss < KMAC; ++ss) {    // issue all loads (MLP)
                const int s = KMAC * m + ss;
                v[ss] = ald(ring_in + ((size_t)(s & (RD - 1)) * BB + rg * 16 + lm) * REL + ld);
            }
            #pragma unroll
            for (int ss = 0; ss < KMAC; ++ss) {    // verify tags
                const int s = KMAC * m + ss;
                const unsigned expt = (unsigned)(s + 1);
                const u64* pin = ring_in + ((size_t)(s & (RD - 1)) * BB + rg * 16 + lm) * REL + ld;
                u64 vv = v[ss];
                while ((unsigned)(vv >> 32) != expt) { __builtin_amdgcn_s_sleep(2); vv = ald(pin); }
                xw[ss] = (unsigned)vv;
            }
        }
        // producer backpressure, once per macro (validated R14)
        if (tid == 0 && !LAST && m >= 2) spinc(cons_my, (unsigned)(KMAC * m - 8));
        // install (cols 56..67 u32 of each row stay zero from init)
        if (l > 0 || ld < 50) {
            #pragma unroll
            for (int ss = 0; ss < KMAC; ++ss)
                ((unsigned*)sx)[ss * 1088 + lm * 68 + ld] = xw[ss];
        }
        barrier_lds();   // install visible; acquire data already in regs
        if (tid == 0 && l > 0) astu(cons_in, (unsigned)(KMAC * m + KMAC));

        // ---- 8 substeps; barriers do NOT drain the ring-store queue ----
        for (int ss = 0; ss < KMAC; ++ss) {
            const int s = KMAC * m + ss;
            // x-part + h-part MFMAs
            f32x4 acc[2] = {{0, 0, 0, 0}, {0, 0, 0, 0}};
            const _Float16* ax = &sx[ss][l16 * 136 + 8 * kg];
            #pragma unroll
            for (int q = 0; q < 4; ++q) {
                const f16x8 a = *(const f16x8*)(ax + 32 * q);
                acc[0] = __builtin_amdgcn_mfma_f32_16x16x32_f16(a, bf[0][q], acc[0], 0, 0, 0);
                acc[1] = __builtin_amdgcn_mfma_f32_16x16x32_f16(a, bf[1][q], acc[1], 0, 0, 0);
            }
            const _Float16* ah = &sh[l16 * 136 + 8 * kg];
            #pragma unroll
            for (int q = 4; q < 8; ++q) {
                const f16x8 a = *(const f16x8*)(ah + 32 * (q - 4));
                acc[0] = __builtin_amdgcn_mfma_f32_16x16x32_f16(a, bf[0][q], acc[0], 0, 0, 0);
                acc[1] = __builtin_amdgcn_mfma_f32_16x16x32_f16(a, bf[1][q], acc[1], 0, 0, 0);
            }
            // activation -> gl. C map: row=4*kg+r, col=l16 (validated).
            #pragma unroll
            for (int t = 0; t < 2; ++t) {
                const int n = 16 * (2 * w + t) + l16;
                if (n < G4) {
                    const bool istanh = (n >= 2 * H) && (n < 3 * H);
                    #pragma unroll
                    for (int r = 0; r < 4; ++r)
                        gl[(4 * kg + r) * GST + n] = act_gate(acc[t][r] + bias[t], istanh);
                }
            }
            barrier_lds();   // B1: gates ready; sh reads of this substep done

            // state update + publish (fire-and-forget tagged u64 stores)
            if (tid < 848) {
                const float* gm = gl + um * GST;
                const float2 vi = *(const float2*)(gm + 2 * up);
                const float2 vf = *(const float2*)(gm + H + 2 * up);
                const float2 vg = *(const float2*)(gm + 2 * H + 2 * up);
                const float2 vo = *(const float2*)(gm + 3 * H + 2 * up);
                c0 = fmaf(vf.x, c0, vi.x * vg.x);
                c1 = fmaf(vf.y, c1, vi.y * vg.y);
                const float h0 = vo.x * fast_tanh(c0);
                const float h1 = vo.y * fast_tanh(c1);
                const unsigned hw = packh2(h0, h1);
                ((unsigned*)sh)[um * 68 + up] = hw;
                if (LAST) {
                    *(float2*)(yout + ((size_t)s * BB + rg * 16 + um) * H + 2 * up) =
                        make_float2(h0, h1);
                } else {
                    ast(ring_out + ((size_t)(s & (RD - 1)) * BB + rg * 16 + um) * REL + up,
                        ((u64)(unsigned)(s + 1) << 32) | hw);
                }
            } else if (!LAST) {   // pad elements 53..55 = 0, tagged
                const int t2 = tid - 848, mm = t2 / 3, dd = t2 % 3;
                ast(ring_out + ((size_t)(s & (RD - 1)) * BB + rg * 16 + mm) * REL + 53 + dd,
                    (u64)(unsigned)(s + 1) << 32);
            }
            barrier_lds();   // B2: h_s visible for next substep (no vmcnt drain)
        }
    }
}
}  // namespace

extern "C" void kernel_launch(void* const* d_in, const int* in_sizes, int n_in,
                              void* d_out, int out_size, void* d_ws, size_t ws_size,
                              hipStream_t stream) {
    const float* noise = (const float*)d_in[0];
    const float* W_ih0 = (const float*)d_in[1];
    const float* W_hh0 = (const float*)d_in[2];
    const float* b_ih0 = (const float*)d_in[3];
    const float* b_hh0 = (const float*)d_in[4];
    const float* W_ih  = (const float*)d_in[5];
    const float* W_hh  = (const float*)d_in[6];
    const float* b_ih  = (const float*)d_in[7];
    const float* b_hh  = (const float*)d_in[8];

    // clear counters + rings each call (replay-safe)
    const size_t clear_bytes = RING_OFF_B + (size_t)10 * RING_PER_L * sizeof(u64);
    hipMemsetAsync(d_ws, 0, clear_bytes, stream);

    unsigned* cnt = (unsigned*)d_ws;
    u64* ring = (u64*)((char*)d_ws + RING_OFF_B);

    lstm_wave<<<dim3(NLAYER * RGN), dim3(NTHR), 0, stream>>>(
        noise, (float*)d_out, cnt, ring,
        W_ih0, W_hh0, b_ih0, b_hh0, W_ih, W_hh, b_ih, b_hh);
}